// Round 6
// baseline (971.339 us; speedup 1.0000x reference)
//
#include <hip/hip_runtime.h>
#include <math.h>

// ---------------------------------------------------------------------------
// HierarchicalTimeAttention on MI355X — no-staging fused edge pass, v6.
//
//   p    = nf @ (Wq@Wk^T) + bq@Wk^T          [N,128]
//   qb_n = nf_n . (Wq bk) + bq.bk            [N]
//   counting-sort edges by src (count -> scan -> scatter, + window bsearch)
//   k_fused6: block owns nodes starting in its 128-edge window (span<=160).
//     Phase A (16 lanes/edge, 2 edges/group, 32 edges/pass, tf pipelined
//       1 pass ahead): t->regs, attn dot vs p[src] (L2-hot), sims vs ce
//       streamed from LDS per-cluster (amortized over 2 reg-held edges),
//       16-lane butterfly, ex=exp, LDS-atomic per-(node,cluster) D,C.
//     Phase B: scl[e] = ex_e * rcp(D_c*C_c)
//     Phase C: 8 teams x 32 lanes x float4: re-read tf rows from L2
//       (NO LDS staging — rows are L2-resident), segmented register sums.
//   out = relu( (agg @ (Wv@Wo) + sw * (bv@Wo)) * (1/nne) + bo )
//
// LDS ~13KB, __launch_bounds__(256,6) -> 6 blocks/CU (24 waves): TLP is the
// lever — round-5 analysis showed >90% stall cycles at 4 blocks/CU.
// NOTE: dur_us includes ~370us of harness workspace re-poison fills.
// ---------------------------------------------------------------------------

#define NN 50000
#define NE 600000
#define DD 128
#define NC 8
#define WIN 128             // sorted-edge window per block
#define NWIN 4688           // ceil(NE/WIN)
#define NBF  4689           // blockFirst entries (0..NWIN)
#define EC 160              // max resident span (span = 127 + deg(last))
#define NLOC 32             // max nodes per greedy sub-range
#define SCALEF 0.08838834764831845f

// ---- workspace element offsets (fp32/int32 units) ----
// zeroed region:
#define OFF_NODECNT  0          // 50000 i32
#define OFF_FILL     50000      // 50000 i32
#define OFF_MASK     100000     // 256 i32
#define ZERO_ELEMS   100256
// non-zeroed (fully written each call):
#define OFF_NODEOFF  100352     // 50000 i32
#define OFF_PARTIAL  150352     // 256 i32
#define OFF_BF       150608     // 4689 i32 (pad)
#define OFF_BQK      160000     // 128 f32
#define OFF_BVO      160128     // 128 f32
#define OFF_WQBK     160256     // 128 f32
#define OFF_C0       160384     // 1 f32 (pad 16)
#define OFF_WQK      160400     // 16384 f32
#define OFF_WVO      176784     // 16384 f32
#define OFF_QB       193168     // 50000 f32
#define OFF_SORTED   243168     // 600000 i32
#define OFF_SRCS     843168     // 600000 i32
#define OFF_SW       1443168    // 50000 f32
#define OFF_P        1493168    // 6,400,000 f32 (agg aliases p: row n written only
                                //  by its owner block after all reads of p[n])
// total: 7,893,168 elems = ~31.6 MB

__device__ __forceinline__ float dot4(float4 a, float4 b) {
  return a.x * b.x + a.y * b.y + a.z * b.z + a.w * b.w;
}

// --- precompute Wqk = Wq@Wk^T, Wvo = Wv@Wo, bqk, bvo, wqbk, c0
//     + (folded) edge-count histogram over src nodes ---
__global__ __launch_bounds__(256) void k_pre_count(
    const float* __restrict__ Wq, const float* __restrict__ bq,
    const float* __restrict__ Wk, const float* __restrict__ bk,
    const float* __restrict__ Wv, const float* __restrict__ bv,
    const float* __restrict__ Wo, const int* __restrict__ ei,
    int* __restrict__ node_cnt,
    float* __restrict__ Wqk, float* __restrict__ bqk,
    float* __restrict__ Wvo, float* __restrict__ bvo,
    float* __restrict__ wqbk, float* __restrict__ c0) {
  int bid = blockIdx.x, t = threadIdx.x;
  if (bid >= 129) {   // edge-count part: no barriers on this path
    long e = (long)(bid - 129) * 256 + t;
    if (e < NE) atomicAdd(&node_cnt[ei[e]], 1);
    return;
  }
  __shared__ float rq[DD], rv[DD];
  int b = bid;
  if (b < DD) {
    if (t < DD) { rq[t] = Wq[b * DD + t]; rv[t] = Wv[b * DD + t]; }
    __syncthreads();
    if (t < DD) {
      float aq = 0.f, av = 0.f;
      for (int j = 0; j < DD; j++) {
        aq += rq[j] * Wk[t * DD + j];   // Wqk[b,t] = Wq row b . Wk row t
        av += rv[j] * Wo[j * DD + t];   // Wvo[b,t] = Wv row b . Wo col t
      }
      Wqk[b * DD + t] = aq;
      Wvo[b * DD + t] = av;
    }
  } else {
    if (t < DD) {
      float a1 = 0.f, a2 = 0.f, a3 = 0.f;
      for (int j = 0; j < DD; j++) {
        a1 += bq[j] * Wk[t * DD + j];
        a2 += bv[j] * Wo[j * DD + t];
        a3 += Wq[t * DD + j] * bk[j];
      }
      bqk[t] = a1; bvo[t] = a2; wqbk[t] = a3;
      if (t == 0) {
        float s = 0.f;
        for (int j = 0; j < DD; j++) s += bq[j] * bk[j];
        *c0 = s;
      }
    }
  }
}

// --- p = nf @ Wqk + bqk ; qb = nf . wqbk + c0 --- (64-row tiles, 256 thr)
__global__ __launch_bounds__(256) void k_p(
    const float* __restrict__ nf, const float* __restrict__ Wqk,
    const float* __restrict__ bqk, const float* __restrict__ wqbk,
    const float* __restrict__ c0p,
    float* __restrict__ p, float* __restrict__ qb) {
  __shared__ float a_lds[64 * DD];
  __shared__ float wb_lds[DD];
  int t = threadIdx.x;
  long row0 = (long)blockIdx.x * 64;
  for (int it = 0; it < 8; it++) {
    int idx = (it * 256 + t) * 4;
    long r = row0 + idx / DD;
    float4 v = {0.f, 0.f, 0.f, 0.f};
    if (r < NN) v = *(const float4*)(nf + r * DD + (idx % DD));
    *(float4*)(a_lds + idx) = v;
  }
  if (t < DD) wb_lds[t] = wqbk[t];
  __syncthreads();
  int cg = t % 32, rg = t / 32;
  int col0 = cg * 4, r0 = rg * 8;
  float acc[8][4]; float qacc[8];
  for (int r = 0; r < 8; r++) { qacc[r] = 0.f; for (int c = 0; c < 4; c++) acc[r][c] = 0.f; }
  for (int k = 0; k < DD; k++) {
    float4 b4 = *(const float4*)(Wqk + k * DD + col0);
    float wbk = wb_lds[k];
    for (int r = 0; r < 8; r++) {
      float a = a_lds[(r0 + r) * DD + k];
      acc[r][0] += a * b4.x; acc[r][1] += a * b4.y;
      acc[r][2] += a * b4.z; acc[r][3] += a * b4.w;
      qacc[r] += a * wbk;
    }
  }
  float4 bq4 = *(const float4*)(bqk + col0);
  float c0v = *c0p;
  for (int r = 0; r < 8; r++) {
    long row = row0 + r0 + r;
    if (row < NN) {
      float4 o;
      o.x = acc[r][0] + bq4.x; o.y = acc[r][1] + bq4.y;
      o.z = acc[r][2] + bq4.z; o.w = acc[r][3] + bq4.w;
      *(float4*)(p + row * DD + col0) = o;
      if (cg == 0) qb[row] = qacc[r] + c0v;
    }
  }
}

// --- prefix scan of node_cnt (3 kernels) ---
__global__ __launch_bounds__(256) void k_scan1(const int* __restrict__ node_cnt,
                                               int* __restrict__ partial) {
  int i = blockIdx.x * 256 + threadIdx.x;
  int v = (i < NN) ? node_cnt[i] : 0;
  for (int o = 1; o < 64; o <<= 1) v += __shfl_xor(v, o);
  __shared__ int wsum[4];
  if ((threadIdx.x & 63) == 0) wsum[threadIdx.x >> 6] = v;
  __syncthreads();
  if (threadIdx.x == 0) partial[blockIdx.x] = wsum[0] + wsum[1] + wsum[2] + wsum[3];
}

__global__ __launch_bounds__(256) void k_scan2(int* __restrict__ partial) {
  __shared__ int s[256];
  int t = threadIdx.x;
  int v = (t < 196) ? partial[t] : 0;
  s[t] = v;
  __syncthreads();
  for (int o = 1; o < 256; o <<= 1) {
    int add = (t >= o) ? s[t - o] : 0;
    __syncthreads();
    s[t] += add;
    __syncthreads();
  }
  if (t < 196) partial[t] = s[t] - v;  // exclusive
}

__global__ __launch_bounds__(256) void k_scan3(const int* __restrict__ node_cnt,
                                               const int* __restrict__ partial,
                                               int* __restrict__ node_off) {
  __shared__ int s[256];
  int t = threadIdx.x;
  int i = blockIdx.x * 256 + t;
  int v = (i < NN) ? node_cnt[i] : 0;
  s[t] = v;
  __syncthreads();
  for (int o = 1; o < 256; o <<= 1) {
    int add = (t >= o) ? s[t - o] : 0;
    __syncthreads();
    s[t] += add;
    __syncthreads();
  }
  if (i < NN) node_off[i] = partial[blockIdx.x] + s[t] - v;
}

// --- counting-sort scatter (+ folded window lower_bound table) ---
#define EDGE_BLKS 2344      // ceil(NE/256)
#define BS_BLKS   19        // ceil(NBF/256)
__global__ __launch_bounds__(256) void k_scatter(const int* __restrict__ ei,
                                                 const int* __restrict__ node_off,
                                                 int* __restrict__ fill,
                                                 int* __restrict__ sorted,
                                                 int* __restrict__ srcs,
                                                 int* __restrict__ blockFirst) {
  int bid = blockIdx.x, t = threadIdx.x;
  if (bid >= EDGE_BLKS) {
    int w = (bid - EDGE_BLKS) * 256 + t;
    if (w < NBF) {
      int v = w * WIN, lo = 0, hi = NN;
      while (lo < hi) { int mid = (lo + hi) >> 1; if (node_off[mid] < v) lo = mid + 1; else hi = mid; }
      blockFirst[w] = lo;   // first n with off[n] >= w*WIN
    }
    return;
  }
  long e = (long)bid * 256 + t;
  if (e < NE) {
    int s = ei[e];
    int pos = node_off[s] + atomicAdd(&fill[s], 1);
    sorted[pos] = (int)e;
    srcs[pos] = s;
  }
}

// --- one-edge ex/argmax helper (fallback path; 16 lanes, valid on jA==0) ---
__device__ __forceinline__ void edge_ex_bc(
    const float* __restrict__ tf, const float* __restrict__ p,
    const float* ce_lds, float qbv, long eid, int src, int jA,
    float& ex, int& bc) {
  const float* tr = tf + eid * DD;
  float4 t0 = *(const float4*)(tr + jA * 4);
  float4 t1 = *(const float4*)(tr + 64 + jA * 4);
  const float* pr = p + (long)src * DD;
  float a = dot4(t0, *(const float4*)(pr + jA * 4)) +
            dot4(t1, *(const float4*)(pr + 64 + jA * 4));
  float s[NC];
  #pragma unroll
  for (int c = 0; c < NC; c++)
    s[c] = dot4(t0, *(const float4*)(ce_lds + c * DD + jA * 4)) +
           dot4(t1, *(const float4*)(ce_lds + c * DD + 64 + jA * 4));
  #pragma unroll
  for (int c = 0; c < NC; c++) {
    s[c] += __shfl_xor(s[c], 1); s[c] += __shfl_xor(s[c], 2);
    s[c] += __shfl_xor(s[c], 4); s[c] += __shfl_xor(s[c], 8);
  }
  a += __shfl_xor(a, 1); a += __shfl_xor(a, 2);
  a += __shfl_xor(a, 4); a += __shfl_xor(a, 8);
  float best = s[0]; bc = 0;
  #pragma unroll
  for (int c = 1; c < NC; c++) if (s[c] > best) { best = s[c]; bc = c; }
  ex = expf((a + qbv) * SCALEF);
}

// --- fused edge pass: no t-staging, ce streamed from LDS, 6 blocks/CU ---
__global__ __launch_bounds__(256, 6) void k_fused6(
    const float* __restrict__ tf, const int* __restrict__ sorted,
    const int* __restrict__ srcs, const int* __restrict__ node_off,
    const int* __restrict__ node_cnt, const int* __restrict__ blockFirst,
    const float* __restrict__ ce, const float* __restrict__ p,
    const float* __restrict__ qb, int* __restrict__ maskArr,
    float* __restrict__ agg, float* __restrict__ sw) {
  __shared__ float ce_lds[NC * DD];     // 4 KB
  __shared__ float exf_sh[EC];
  __shared__ float scl_sh[EC];
  __shared__ int   cli_sh[EC];
  __shared__ int   offL_sh[NLOC];
  __shared__ int   cntL_sh[NLOC];
  __shared__ float qb_sh[NLOC];
  __shared__ float D_sh[NLOC * NC];     // 1 KB
  __shared__ int   C_sh[NLOC * NC];     // 1 KB
  __shared__ float comb[8 * DD];        // 4 KB (fallback team-combine only)
  __shared__ int   ctrl[4];             // 0:nN 1:span 2:eb

  int t = threadIdx.x, b = blockIdx.x;
  int fn = blockFirst[b], ln = blockFirst[b + 1] - 1;
  if (fn >= NN || ln < fn) return;   // window owns no node starts

  *(float4*)(ce_lds + t * 4) = *(const float4*)(ce + t * 4);  // 256*4 = 1024

  int g = t >> 4, jA = t & 15;             // Phase A: 16 groups x 16 lanes
  int team = t >> 5, c4 = t & 31;          // Phase C: 8 teams x 32 float4-cols
  int msk = 0;

  int s0 = fn;
  while (s0 <= ln) {
    // ---- wave 0: greedy node-prefix pick + per-node staging ----
    if (t < 64) {
      int offv = 0, cntv = 0; bool fit = false;
      bool valid = (t < NLOC && s0 + t <= ln);
      if (valid) { offv = node_off[s0 + t]; cntv = node_cnt[s0 + t]; }
      int off0 = __shfl(offv, 0);
      if (valid) {
        fit = (offv - off0 + cntv) <= EC;
        offL_sh[t] = offv - off0; cntL_sh[t] = cntv; qb_sh[t] = qb[s0 + t];
      }
      unsigned long long bm = __ballot(fit);
      int pref = (int)__popcll(bm);        // fit is a monotone prefix
      if (t == 0) { ctrl[0] = pref; ctrl[2] = off0; }
      if (pref > 0 && t == pref - 1) ctrl[1] = offv - off0 + cntv;  // span
    }
    for (int i = t; i < NLOC * NC; i += 256) { D_sh[i] = 0.f; C_sh[i] = 0; }
    __syncthreads();
    int nN = ctrl[0], eb = ctrl[2];

    if (nN == 0) {
      // ---- pathological single node with > EC edges: chunked two-pass ----
      int cnt = cntL_sh[0];
      float qbv0 = qb_sh[0];
      for (int base = 0; base < cnt; base += 32) {   // pass 1: D,C only
        #pragma unroll
        for (int q = 0; q < 2; q++) {
          int e = base + 2 * g + q;
          if (e < cnt) {
            float ex; int bc;
            edge_ex_bc(tf, p, ce_lds, qbv0, (long)sorted[eb + e], s0, jA, ex, bc);
            if (jA == 0) {
              atomicAdd(&D_sh[bc], ex);
              atomicAdd(&C_sh[bc], 1);
            }
          }
        }
      }
      __syncthreads();
      float4 r = {0.f, 0.f, 0.f, 0.f};
      for (int c0 = 0; c0 < cnt; c0 += EC) {        // pass 2: recompute + agg
        int m = cnt - c0; if (m > EC) m = EC;
        for (int base = 0; base < m; base += 32) {
          #pragma unroll
          for (int q = 0; q < 2; q++) {
            int e = base + 2 * g + q;
            if (e < m) {
              float ex; int bc;
              edge_ex_bc(tf, p, ce_lds, qbv0, (long)sorted[eb + c0 + e], s0, jA, ex, bc);
              if (jA == 0) { exf_sh[e] = ex; cli_sh[e] = bc; }
            }
          }
        }
        __syncthreads();
        if (t < m) {
          int c = cli_sh[t];
          scl_sh[t] = exf_sh[t] * __builtin_amdgcn_rcpf(D_sh[c] * (float)C_sh[c]);
        }
        __syncthreads();
        for (int e = team; e < m; e += 8) {
          float s = scl_sh[e];
          const float4 tv = *(const float4*)(tf + (long)sorted[eb + c0 + e] * DD + c4 * 4);
          r.x += s * tv.x; r.y += s * tv.y; r.z += s * tv.z; r.w += s * tv.w;
        }
        __syncthreads();
      }
      *(float4*)(comb + team * DD + c4 * 4) = r;    // 8-team combine
      __syncthreads();
      if (t < DD) {
        float acc = 0.f;
        #pragma unroll
        for (int tm = 0; tm < 8; tm++) acc += comb[tm * DD + t];
        agg[(long)s0 * DD + t] = acc;
      }
      if (t == 0) {
        float ssw = 0.f; int mk = 0;
        #pragma unroll
        for (int c = 0; c < NC; c++) {
          int cc = C_sh[c];
          if (cc > 0) { mk |= 1 << c; ssw += __builtin_amdgcn_rcpf((float)cc); }
        }
        sw[s0] = ssw; msk |= mk;
      }
      __syncthreads();
      s0 += 1;
      continue;
    }

    int span = ctrl[1];

    // ---- Phase A: 32 edges/pass (2/group), tf pipelined 1 pass ahead ----
    int e0 = 2 * g, e1 = 2 * g + 1;
    float4 ta0 = {0,0,0,0}, ta1 = {0,0,0,0}, tb0 = {0,0,0,0}, tb1 = {0,0,0,0};
    if (e0 < span) {
      const float* tr = tf + (long)sorted[eb + e0] * DD;
      ta0 = *(const float4*)(tr + jA * 4);
      ta1 = *(const float4*)(tr + 64 + jA * 4);
    }
    if (e1 < span) {
      const float* tr = tf + (long)sorted[eb + e1] * DD;
      tb0 = *(const float4*)(tr + jA * 4);
      tb1 = *(const float4*)(tr + 64 + jA * 4);
    }
    for (int base = 0; base < span; base += 32) {
      int ce0 = base + 2 * g, ce1 = ce0 + 1;
      int ne0 = ce0 + 32, ne1 = ce1 + 32;
      float4 na0 = {0,0,0,0}, na1 = {0,0,0,0}, nb0 = {0,0,0,0}, nb1 = {0,0,0,0};
      if (ne0 < span) {
        const float* tr = tf + (long)sorted[eb + ne0] * DD;
        na0 = *(const float4*)(tr + jA * 4);
        na1 = *(const float4*)(tr + 64 + jA * 4);
      }
      if (ne1 < span) {
        const float* tr = tf + (long)sorted[eb + ne1] * DD;
        nb0 = *(const float4*)(tr + jA * 4);
        nb1 = *(const float4*)(tr + 64 + jA * 4);
      }
      // p-dots first (short-lived p regs), then ce streaming
      int sA = 0, sB = 0;
      float a0 = 0.f, a1 = 0.f;
      if (ce0 < span) {
        sA = srcs[eb + ce0];
        const float* pr = p + (long)sA * DD;
        a0 = dot4(ta0, *(const float4*)(pr + jA * 4)) +
             dot4(ta1, *(const float4*)(pr + 64 + jA * 4));
      }
      if (ce1 < span) {
        sB = srcs[eb + ce1];
        const float* pr = p + (long)sB * DD;
        a1 = dot4(tb0, *(const float4*)(pr + jA * 4)) +
             dot4(tb1, *(const float4*)(pr + 64 + jA * 4));
      }
      float s0v[NC], s1v[NC];
      #pragma unroll
      for (int c = 0; c < NC; c++) {
        float4 cf0 = *(const float4*)(ce_lds + c * DD + jA * 4);
        float4 cf1 = *(const float4*)(ce_lds + c * DD + 64 + jA * 4);
        s0v[c] = dot4(ta0, cf0) + dot4(ta1, cf1);
        s1v[c] = dot4(tb0, cf0) + dot4(tb1, cf1);
      }
      #pragma unroll
      for (int c = 0; c < NC; c++) {
        s0v[c] += __shfl_xor(s0v[c], 1); s0v[c] += __shfl_xor(s0v[c], 2);
        s0v[c] += __shfl_xor(s0v[c], 4); s0v[c] += __shfl_xor(s0v[c], 8);
        s1v[c] += __shfl_xor(s1v[c], 1); s1v[c] += __shfl_xor(s1v[c], 2);
        s1v[c] += __shfl_xor(s1v[c], 4); s1v[c] += __shfl_xor(s1v[c], 8);
      }
      a0 += __shfl_xor(a0, 1); a0 += __shfl_xor(a0, 2);
      a0 += __shfl_xor(a0, 4); a0 += __shfl_xor(a0, 8);
      a1 += __shfl_xor(a1, 1); a1 += __shfl_xor(a1, 2);
      a1 += __shfl_xor(a1, 4); a1 += __shfl_xor(a1, 8);
      if (jA == 0) {
        if (ce0 < span) {
          float best = s0v[0]; int bc = 0;
          #pragma unroll
          for (int c = 1; c < NC; c++) if (s0v[c] > best) { best = s0v[c]; bc = c; }
          float ex = expf((a0 + qb_sh[sA - s0]) * SCALEF);
          exf_sh[ce0] = ex; cli_sh[ce0] = bc;
          atomicAdd(&D_sh[(sA - s0) * NC + bc], ex);
          atomicAdd(&C_sh[(sA - s0) * NC + bc], 1);
        }
        if (ce1 < span) {
          float best = s1v[0]; int bc = 0;
          #pragma unroll
          for (int c = 1; c < NC; c++) if (s1v[c] > best) { best = s1v[c]; bc = c; }
          float ex = expf((a1 + qb_sh[sB - s0]) * SCALEF);
          exf_sh[ce1] = ex; cli_sh[ce1] = bc;
          atomicAdd(&D_sh[(sB - s0) * NC + bc], ex);
          atomicAdd(&C_sh[(sB - s0) * NC + bc], 1);
        }
      }
      ta0 = na0; ta1 = na1; tb0 = nb0; tb1 = nb1;
    }
    __syncthreads();

    // ---- Phase B: parallel scale ----
    if (t < span) {
      int l = (srcs[eb + t] - s0) * NC + cli_sh[t];
      scl_sh[t] = exf_sh[t] * __builtin_amdgcn_rcpf(D_sh[l] * (float)C_sh[l]);
    }
    __syncthreads();

    // ---- Phase C: segmented register sums, tf rows re-read from L2 ----
    for (int k = team; k < nN; k += 8) {
      float4 r = {0.f, 0.f, 0.f, 0.f};
      int eS = offL_sh[k], eE = eS + cntL_sh[k];
      for (int e = eS; e < eE; e++) {
        float s = scl_sh[e];
        const float4 tv = *(const float4*)(tf + (long)sorted[eb + e] * DD + c4 * 4);
        r.x += s * tv.x; r.y += s * tv.y; r.z += s * tv.z; r.w += s * tv.w;
      }
      long n = s0 + k;
      *(float4*)(agg + n * DD + c4 * 4) = r;
      if (c4 == 0) {
        float ssw = 0.f; int mk = 0;
        #pragma unroll
        for (int c = 0; c < NC; c++) {
          int cc = C_sh[k * NC + c];
          if (cc > 0) { mk |= 1 << c; ssw += __builtin_amdgcn_rcpf((float)cc); }
        }
        sw[n] = ssw; msk |= mk;
      }
    }
    __syncthreads();
    s0 += nN;
  }
  if ((t & 31) == 0 && msk) atomicOr(&maskArr[b & 255], msk);
}

// --- out = relu((agg @ Wvo + sw*bvo) * inv_nne + bo); inv_nne from maskArr ---
__global__ __launch_bounds__(256) void k_out(
    const float* __restrict__ agg, const float* __restrict__ Wvo,
    const float* __restrict__ bvo, const float* __restrict__ sw,
    const float* __restrict__ bo, const int* __restrict__ maskArr,
    float* __restrict__ out) {
  __shared__ float a_lds[64 * DD];
  __shared__ float sw_lds[64];
  __shared__ int morw[4];
  int t = threadIdx.x;
  int mv = maskArr[t];
  for (int o = 1; o < 64; o <<= 1) mv |= __shfl_xor(mv, o);
  if ((t & 63) == 0) morw[t >> 6] = mv;
  long row0 = (long)blockIdx.x * 64;
  for (int it = 0; it < 8; it++) {
    int idx = (it * 256 + t) * 4;
    long r = row0 + idx / DD;
    float4 v = {0.f, 0.f, 0.f, 0.f};
    if (r < NN) v = *(const float4*)(agg + r * DD + (idx % DD));
    *(float4*)(a_lds + idx) = v;
  }
  if (t < 64) {
    long r = row0 + t;
    sw_lds[t] = (r < NN) ? sw[r] : 0.f;
  }
  __syncthreads();
  int full = morw[0] | morw[1] | morw[2] | morw[3];
  int nne = __popc(full); if (nne == 0) nne = 1;
  float inv = 1.0f / (float)nne;
  int cg = t % 32, rg = t / 32;
  int col0 = cg * 4, r0 = rg * 8;
  float acc[8][4];
  for (int r = 0; r < 8; r++) for (int c = 0; c < 4; c++) acc[r][c] = 0.f;
  for (int k = 0; k < DD; k++) {
    float4 b4 = *(const float4*)(Wvo + k * DD + col0);
    for (int r = 0; r < 8; r++) {
      float a = a_lds[(r0 + r) * DD + k];
      acc[r][0] += a * b4.x; acc[r][1] += a * b4.y;
      acc[r][2] += a * b4.z; acc[r][3] += a * b4.w;
    }
  }
  float4 bv4 = *(const float4*)(bvo + col0);
  float4 bo4 = *(const float4*)(bo + col0);
  for (int r = 0; r < 8; r++) {
    long row = row0 + r0 + r;
    if (row < NN) {
      float s = sw_lds[r0 + r];
      float4 o;
      o.x = fmaxf((acc[r][0] + s * bv4.x) * inv + bo4.x, 0.f);
      o.y = fmaxf((acc[r][1] + s * bv4.y) * inv + bo4.y, 0.f);
      o.z = fmaxf((acc[r][2] + s * bv4.z) * inv + bo4.z, 0.f);
      o.w = fmaxf((acc[r][3] + s * bv4.w) * inv + bo4.w, 0.f);
      *(float4*)(out + row * DD + col0) = o;
    }
  }
}

extern "C" void kernel_launch(void* const* d_in, const int* in_sizes, int n_in,
                              void* d_out, int out_size, void* d_ws, size_t ws_size,
                              hipStream_t stream) {
  const float* nf = (const float*)d_in[0];
  const float* tf = (const float*)d_in[1];
  // d_in[2] = context_feat: unused by the reference
  const int*   ei = (const int*)d_in[3];   // row 0 = src
  const float* Wq = (const float*)d_in[4];
  const float* bq = (const float*)d_in[5];
  const float* Wk = (const float*)d_in[6];
  const float* bk = (const float*)d_in[7];
  const float* Wv = (const float*)d_in[8];
  const float* bv = (const float*)d_in[9];
  const float* ce = (const float*)d_in[10];
  const float* Wo = (const float*)d_in[11];
  const float* bo = (const float*)d_in[12];
  float* out = (float*)d_out;

  float* ws  = (float*)d_ws;
  int*   node_cnt = (int*)(ws + OFF_NODECNT);
  int*   fill     = (int*)(ws + OFF_FILL);
  int*   maskArr  = (int*)(ws + OFF_MASK);
  int*   node_off = (int*)(ws + OFF_NODEOFF);
  int*   partial  = (int*)(ws + OFF_PARTIAL);
  int*   blockFirst = (int*)(ws + OFF_BF);
  float* bqk      = ws + OFF_BQK;
  float* bvo      = ws + OFF_BVO;
  float* wqbk     = ws + OFF_WQBK;
  float* c0       = ws + OFF_C0;
  float* Wqk      = ws + OFF_WQK;
  float* Wvo      = ws + OFF_WVO;
  float* qb       = ws + OFF_QB;
  int*   sorted   = (int*)(ws + OFF_SORTED);
  int*   srcs     = (int*)(ws + OFF_SRCS);
  float* sw       = ws + OFF_SW;
  float* p        = ws + OFF_P;   // [N,128]
  float* agg      = ws + OFF_P;   // aliased (ownership-safe)

  hipMemsetAsync(d_ws, 0, (size_t)ZERO_ELEMS * 4, stream);

  k_pre_count<<<129 + EDGE_BLKS, 256, 0, stream>>>(
      Wq, bq, Wk, bk, Wv, bv, Wo, ei, node_cnt, Wqk, bqk, Wvo, bvo, wqbk, c0);
  k_p<<<(NN + 63) / 64, 256, 0, stream>>>(nf, Wqk, bqk, wqbk, c0, p, qb);
  k_scan1<<<196, 256, 0, stream>>>(node_cnt, partial);
  k_scan2<<<1, 256, 0, stream>>>(partial);
  k_scan3<<<196, 256, 0, stream>>>(node_cnt, partial, node_off);
  k_scatter<<<EDGE_BLKS + BS_BLKS, 256, 0, stream>>>(ei, node_off, fill, sorted,
                                                     srcs, blockFirst);
  k_fused6<<<NWIN, 256, 0, stream>>>(tf, sorted, srcs, node_off, node_cnt,
                                     blockFirst, ce, p, qb, maskArr, agg, sw);
  k_out<<<(NN + 63) / 64, 256, 0, stream>>>(agg, Wvo, bvo, sw, bo, maskArr, out);
}

// Round 7
// 702.323 us; speedup vs baseline: 1.3830x; 1.3830x over previous
//
#include <hip/hip_runtime.h>
#include <math.h>

// ---------------------------------------------------------------------------
// HierarchicalTimeAttention on MI355X — bulk-staged resident-span pass, v7.
//
//   p    = nf @ (Wq@Wk^T) + bq@Wk^T          [N,128]
//   qb_n = nf_n . (Wq bk) + bq.bk            [N]
//   counting-sort edges by src (count -> scan -> scatter, + window bsearch)
//   k_fused7: block owns nodes starting in its 56-edge window; greedy node
//     prefix with span <= EC=70 resident LDS rows (usually the whole window).
//     Phase S: BULK stage — all span rows loaded with ~32 rows in flight
//       (4 float4/thread/batch), swizzled ds_write, ONE vmcnt drain per
//       sub-range (v5 paid HBM latency every 16-edge pass; v6 showed
//       dropping LDS staging re-reads 5.6x from HBM — staging stays).
//     Phase A (16 lanes/edge): t from LDS (2 ds_read_b128), p[src] from
//       global (L1-hot: sorted edges reuse rows), sims vs ce in VGPRs,
//       16-lane butterfly, ex=exp, LDS-atomic per-(node,cluster) D,C.
//     Phase B: scl[e] = ex_e * rcp(D_c*C_c)
//     Phase C: 8 teams x 32 lanes x float4 cols from t_lds (XOR slots).
//   out = relu( (agg @ (Wv@Wo) + sw * (bv@Wo)) * (1/nne) + bo )
//
// LDS ~38.8KB -> 4 blocks/CU. NOTE: dur_us includes ~370us of harness
// workspace re-poison fills (2x185us, 1.2GB) — outside our control.
// ---------------------------------------------------------------------------

#define NN 50000
#define NE 600000
#define DD 128
#define NC 8
#define WIN 56              // sorted-edge window per block
#define NWIN 10715          // ceil(NE/WIN)
#define NBF  10716          // blockFirst entries (0..NWIN)
#define EC 70               // resident edge rows (span = 55 + deg(last) usually fits)
#define NLOC 24             // max nodes per greedy sub-range
#define SCALEF 0.08838834764831845f

// ---- workspace element offsets (fp32/int32 units) ----
// zeroed region:
#define OFF_NODECNT  0          // 50000 i32
#define OFF_FILL     50000      // 50000 i32
#define OFF_MASK     100000     // 256 i32
#define ZERO_ELEMS   100256
// non-zeroed (fully written each call):
#define OFF_NODEOFF  100352     // 50000 i32
#define OFF_PARTIAL  150352     // 256 i32
#define OFF_BF       150608     // 10716 i32 (ends 161324)
#define OFF_BQK      161328     // 128 f32
#define OFF_BVO      161456     // 128 f32
#define OFF_WQBK     161584     // 128 f32
#define OFF_C0       161712     // 1 f32 (pad 16)
#define OFF_WQK      161728     // 16384 f32
#define OFF_WVO      178112     // 16384 f32
#define OFF_QB       194496     // 50000 f32
#define OFF_SORTED   244496     // 600000 i32
#define OFF_SRCS     844496     // 600000 i32
#define OFF_SW       1444496    // 50000 f32
#define OFF_P        1494496    // 6,400,000 f32 (agg aliases p: row n written only
                                //  by its owner block after all reads of p[n])
// total: 7,894,496 elems = ~31.6 MB

__device__ __forceinline__ float dot4(float4 a, float4 b) {
  return a.x * b.x + a.y * b.y + a.z * b.z + a.w * b.w;
}

// --- precompute Wqk = Wq@Wk^T, Wvo = Wv@Wo, bqk, bvo, wqbk, c0
//     + (folded) edge-count histogram over src nodes ---
__global__ __launch_bounds__(256) void k_pre_count(
    const float* __restrict__ Wq, const float* __restrict__ bq,
    const float* __restrict__ Wk, const float* __restrict__ bk,
    const float* __restrict__ Wv, const float* __restrict__ bv,
    const float* __restrict__ Wo, const int* __restrict__ ei,
    int* __restrict__ node_cnt,
    float* __restrict__ Wqk, float* __restrict__ bqk,
    float* __restrict__ Wvo, float* __restrict__ bvo,
    float* __restrict__ wqbk, float* __restrict__ c0) {
  int bid = blockIdx.x, t = threadIdx.x;
  if (bid >= 129) {   // edge-count part: no barriers on this path
    long e = (long)(bid - 129) * 256 + t;
    if (e < NE) atomicAdd(&node_cnt[ei[e]], 1);
    return;
  }
  __shared__ float rq[DD], rv[DD];
  int b = bid;
  if (b < DD) {
    if (t < DD) { rq[t] = Wq[b * DD + t]; rv[t] = Wv[b * DD + t]; }
    __syncthreads();
    if (t < DD) {
      float aq = 0.f, av = 0.f;
      for (int j = 0; j < DD; j++) {
        aq += rq[j] * Wk[t * DD + j];   // Wqk[b,t] = Wq row b . Wk row t
        av += rv[j] * Wo[j * DD + t];   // Wvo[b,t] = Wv row b . Wo col t
      }
      Wqk[b * DD + t] = aq;
      Wvo[b * DD + t] = av;
    }
  } else {
    if (t < DD) {
      float a1 = 0.f, a2 = 0.f, a3 = 0.f;
      for (int j = 0; j < DD; j++) {
        a1 += bq[j] * Wk[t * DD + j];
        a2 += bv[j] * Wo[j * DD + t];
        a3 += Wq[t * DD + j] * bk[j];
      }
      bqk[t] = a1; bvo[t] = a2; wqbk[t] = a3;
      if (t == 0) {
        float s = 0.f;
        for (int j = 0; j < DD; j++) s += bq[j] * bk[j];
        *c0 = s;
      }
    }
  }
}

// --- p = nf @ Wqk + bqk ; qb = nf . wqbk + c0 --- (64-row tiles, 256 thr)
__global__ __launch_bounds__(256) void k_p(
    const float* __restrict__ nf, const float* __restrict__ Wqk,
    const float* __restrict__ bqk, const float* __restrict__ wqbk,
    const float* __restrict__ c0p,
    float* __restrict__ p, float* __restrict__ qb) {
  __shared__ float a_lds[64 * DD];
  __shared__ float wb_lds[DD];
  int t = threadIdx.x;
  long row0 = (long)blockIdx.x * 64;
  for (int it = 0; it < 8; it++) {
    int idx = (it * 256 + t) * 4;
    long r = row0 + idx / DD;
    float4 v = {0.f, 0.f, 0.f, 0.f};
    if (r < NN) v = *(const float4*)(nf + r * DD + (idx % DD));
    *(float4*)(a_lds + idx) = v;
  }
  if (t < DD) wb_lds[t] = wqbk[t];
  __syncthreads();
  int cg = t % 32, rg = t / 32;
  int col0 = cg * 4, r0 = rg * 8;
  float acc[8][4]; float qacc[8];
  for (int r = 0; r < 8; r++) { qacc[r] = 0.f; for (int c = 0; c < 4; c++) acc[r][c] = 0.f; }
  for (int k = 0; k < DD; k++) {
    float4 b4 = *(const float4*)(Wqk + k * DD + col0);
    float wbk = wb_lds[k];
    for (int r = 0; r < 8; r++) {
      float a = a_lds[(r0 + r) * DD + k];
      acc[r][0] += a * b4.x; acc[r][1] += a * b4.y;
      acc[r][2] += a * b4.z; acc[r][3] += a * b4.w;
      qacc[r] += a * wbk;
    }
  }
  float4 bq4 = *(const float4*)(bqk + col0);
  float c0v = *c0p;
  for (int r = 0; r < 8; r++) {
    long row = row0 + r0 + r;
    if (row < NN) {
      float4 o;
      o.x = acc[r][0] + bq4.x; o.y = acc[r][1] + bq4.y;
      o.z = acc[r][2] + bq4.z; o.w = acc[r][3] + bq4.w;
      *(float4*)(p + row * DD + col0) = o;
      if (cg == 0) qb[row] = qacc[r] + c0v;
    }
  }
}

// --- prefix scan of node_cnt (3 kernels) ---
__global__ __launch_bounds__(256) void k_scan1(const int* __restrict__ node_cnt,
                                               int* __restrict__ partial) {
  int i = blockIdx.x * 256 + threadIdx.x;
  int v = (i < NN) ? node_cnt[i] : 0;
  for (int o = 1; o < 64; o <<= 1) v += __shfl_xor(v, o);
  __shared__ int wsum[4];
  if ((threadIdx.x & 63) == 0) wsum[threadIdx.x >> 6] = v;
  __syncthreads();
  if (threadIdx.x == 0) partial[blockIdx.x] = wsum[0] + wsum[1] + wsum[2] + wsum[3];
}

__global__ __launch_bounds__(256) void k_scan2(int* __restrict__ partial) {
  __shared__ int s[256];
  int t = threadIdx.x;
  int v = (t < 196) ? partial[t] : 0;
  s[t] = v;
  __syncthreads();
  for (int o = 1; o < 256; o <<= 1) {
    int add = (t >= o) ? s[t - o] : 0;
    __syncthreads();
    s[t] += add;
    __syncthreads();
  }
  if (t < 196) partial[t] = s[t] - v;  // exclusive
}

__global__ __launch_bounds__(256) void k_scan3(const int* __restrict__ node_cnt,
                                               const int* __restrict__ partial,
                                               int* __restrict__ node_off) {
  __shared__ int s[256];
  int t = threadIdx.x;
  int i = blockIdx.x * 256 + t;
  int v = (i < NN) ? node_cnt[i] : 0;
  s[t] = v;
  __syncthreads();
  for (int o = 1; o < 256; o <<= 1) {
    int add = (t >= o) ? s[t - o] : 0;
    __syncthreads();
    s[t] += add;
    __syncthreads();
  }
  if (i < NN) node_off[i] = partial[blockIdx.x] + s[t] - v;
}

// --- counting-sort scatter (+ folded window lower_bound table) ---
#define EDGE_BLKS 2344      // ceil(NE/256)
#define BS_BLKS   42        // ceil(NBF/256)
__global__ __launch_bounds__(256) void k_scatter(const int* __restrict__ ei,
                                                 const int* __restrict__ node_off,
                                                 int* __restrict__ fill,
                                                 int* __restrict__ sorted,
                                                 int* __restrict__ srcs,
                                                 int* __restrict__ blockFirst) {
  int bid = blockIdx.x, t = threadIdx.x;
  if (bid >= EDGE_BLKS) {
    int w = (bid - EDGE_BLKS) * 256 + t;
    if (w < NBF) {
      int v = w * WIN, lo = 0, hi = NN;
      while (lo < hi) { int mid = (lo + hi) >> 1; if (node_off[mid] < v) lo = mid + 1; else hi = mid; }
      blockFirst[w] = lo;   // first n with off[n] >= w*WIN
    }
    return;
  }
  long e = (long)bid * 256 + t;
  if (e < NE) {
    int s = ei[e];
    int pos = node_off[s] + atomicAdd(&fill[s], 1);
    sorted[pos] = (int)e;
    srcs[pos] = s;
  }
}

// --- Phase A worker (fallback path): one edge, 16 lanes (jA=0..15).
// Lane jA owns logical float4 slots {jA, 16+jA}; staged at slot^e7
// (per-edge permutation -> uniform banks). ce fragments live in VGPRs. ---
__device__ __forceinline__ void phase_a16(
    const float* __restrict__ tf, const float* __restrict__ p,
    const float4 (&ceg)[NC][2], float* t_lds, float* exf_sh, int* cli_sh,
    float* D_sh, int* C_sh,
    int slot, int jA, int eid, int src, int lnode, float qbv,
    bool doStage, bool doDC) {
  const float* trow = tf + (long)eid * DD;
  float4 t0 = *(const float4*)(trow + jA * 4);
  float4 t1 = *(const float4*)(trow + (16 + jA) * 4);
  if (doStage) {
    int e7 = slot & 7;
    *(float4*)(t_lds + slot * DD + ((jA ^ e7) << 2)) = t0;
    *(float4*)(t_lds + slot * DD + ((16 + (jA ^ e7)) << 2)) = t1;
  }
  const float* prow = p + (long)src * DD;
  float4 p0 = *(const float4*)(prow + jA * 4);
  float4 p1 = *(const float4*)(prow + (16 + jA) * 4);
  float a = dot4(t0, p0) + dot4(t1, p1);
  float sims[NC];
  #pragma unroll
  for (int c = 0; c < NC; c++)
    sims[c] = dot4(t0, ceg[c][0]) + dot4(t1, ceg[c][1]);
  #pragma unroll
  for (int c = 0; c < NC; c++) {
    sims[c] += __shfl_xor(sims[c], 1);
    sims[c] += __shfl_xor(sims[c], 2);
    sims[c] += __shfl_xor(sims[c], 4);
    sims[c] += __shfl_xor(sims[c], 8);
  }
  a += __shfl_xor(a, 1);
  a += __shfl_xor(a, 2);
  a += __shfl_xor(a, 4);
  a += __shfl_xor(a, 8);
  if (jA == 0) {
    float best = sims[0]; int bc = 0;
    #pragma unroll
    for (int c = 1; c < NC; c++) if (sims[c] > best) { best = sims[c]; bc = c; }
    float ex = expf((a + qbv) * SCALEF);
    exf_sh[slot] = ex; cli_sh[slot] = bc;
    if (doDC) {
      atomicAdd(&D_sh[lnode * NC + bc], ex);
      atomicAdd(&C_sh[lnode * NC + bc], 1);
    }
  }
}

// --- fused edge pass: bulk stage, LDS-fed Phase A, register aggregation ---
__global__ __launch_bounds__(256, 4) void k_fused7(
    const float* __restrict__ tf, const int* __restrict__ sorted,
    const int* __restrict__ srcs, const int* __restrict__ node_off,
    const int* __restrict__ node_cnt, const int* __restrict__ blockFirst,
    const float* __restrict__ ce, const float* __restrict__ p,
    const float* __restrict__ qb, int* __restrict__ maskArr,
    float* __restrict__ agg, float* __restrict__ sw) {
  __shared__ float t_lds[EC * DD];      // 35 KB (xor-swizzled float4 slots)
  __shared__ float exf_sh[EC];
  __shared__ float scl_sh[EC];
  __shared__ int   cli_sh[EC];
  __shared__ int   srcs_sh[EC];
  __shared__ int   offL_sh[NLOC];
  __shared__ int   cntL_sh[NLOC];
  __shared__ float qb_sh[NLOC];
  __shared__ float D_sh[NLOC * NC];     // 768 B
  __shared__ int   C_sh[NLOC * NC];     // 768 B
  __shared__ int   ctrl[4];             // 0:nN 1:span 2:eb

  int t = threadIdx.x, b = blockIdx.x;
  int fn = blockFirst[b], ln = blockFirst[b + 1] - 1;
  if (fn >= NN || ln < fn) return;   // window owns no node starts

  int elA = t >> 4, jA = t & 15;           // Phase A: 16 edges x 16 lanes
  int team = t >> 5, c4 = t & 31;          // Phase C: 8 teams x 32 float4-cols
  int rR = t >> 3, cL = t & 7;             // Phase S: 32 rows x 8 lanes/row
  int msk = 0;

  // cluster embeddings -> registers (once per kernel): 8 clusters x 2 float4
  float4 ceg[NC][2];
  #pragma unroll
  for (int c = 0; c < NC; c++) {
    ceg[c][0] = *(const float4*)(ce + c * DD + jA * 4);
    ceg[c][1] = *(const float4*)(ce + c * DD + (16 + jA) * 4);
  }

  int s0 = fn;
  while (s0 <= ln) {
    // ---- wave 0: greedy node-prefix pick + per-node staging ----
    if (t < 64) {
      int offv = 0, cntv = 0; bool fit = false;
      bool valid = (t < NLOC && s0 + t <= ln);
      if (valid) { offv = node_off[s0 + t]; cntv = node_cnt[s0 + t]; }
      int off0 = __shfl(offv, 0);
      if (valid) {
        fit = (offv - off0 + cntv) <= EC;
        offL_sh[t] = offv - off0; cntL_sh[t] = cntv; qb_sh[t] = qb[s0 + t];
      }
      unsigned long long bm = __ballot(fit);
      int pref = (int)__popcll(bm);        // fit is a monotone prefix
      if (t == 0) { ctrl[0] = pref; ctrl[2] = off0; }
      if (pref > 0 && t == pref - 1) ctrl[1] = offv - off0 + cntv;  // span
    }
    for (int i = t; i < NLOC * NC; i += 256) { D_sh[i] = 0.f; C_sh[i] = 0; }
    __syncthreads();
    int nN = ctrl[0], eb = ctrl[2];

    if (nN == 0) {
      // ---- pathological single node with > EC edges: chunked two-pass ----
      int cnt = cntL_sh[0];
      float qbv0 = qb_sh[0];
      for (int c0 = 0; c0 < cnt; c0 += 16) {        // pass 1: D,C only
        int el = c0 + elA;
        if (el < cnt)
          phase_a16(tf, p, ceg, t_lds, exf_sh, cli_sh, D_sh, C_sh,
                    elA, jA, sorted[eb + el], s0, 0, qbv0, false, true);
      }
      __syncthreads();
      float4 r = {0.f, 0.f, 0.f, 0.f};
      for (int c0 = 0; c0 < cnt; c0 += EC) {        // pass 2: aggregate
        int m = cnt - c0; if (m > EC) m = EC;
        for (int r0 = 0; r0 < m; r0 += 16) {
          int sl = r0 + elA;
          if (sl < m)
            phase_a16(tf, p, ceg, t_lds, exf_sh, cli_sh, D_sh, C_sh,
                      sl, jA, sorted[eb + c0 + sl], s0, 0, qbv0, true, false);
        }
        __syncthreads();
        if (t < m) {
          int c = cli_sh[t];
          scl_sh[t] = exf_sh[t] * __builtin_amdgcn_rcpf(D_sh[c] * (float)C_sh[c]);
        }
        __syncthreads();
        for (int e = team; e < m; e += 8) {
          float s = scl_sh[e];
          const float4 tv = *(const float4*)(t_lds + e * DD + ((c4 ^ (e & 7)) << 2));
          r.x += s * tv.x; r.y += s * tv.y; r.z += s * tv.z; r.w += s * tv.w;
        }
        __syncthreads();
      }
      *(float4*)(t_lds + team * DD + c4 * 4) = r;   // 8-team combine
      __syncthreads();
      if (t < DD) {
        float acc = 0.f;
        #pragma unroll
        for (int tm = 0; tm < 8; tm++) acc += t_lds[tm * DD + t];
        agg[(long)s0 * DD + t] = acc;
      }
      if (t == 0) {
        float ssw = 0.f; int mk = 0;
        #pragma unroll
        for (int c = 0; c < NC; c++) {
          int cc = C_sh[c];
          if (cc > 0) { mk |= 1 << c; ssw += __builtin_amdgcn_rcpf((float)cc); }
        }
        sw[s0] = ssw; msk |= mk;
      }
      __syncthreads();
      s0 += 1;
      continue;
    }

    int span = ctrl[1];

    // ---- Phase S: bulk stage all span rows + srcs (one vmcnt drain) ----
    // Thread covers row rR (per batch), cols (cL + 8i); stored at slot
    // (col ^ (row&7)) so Phase A/C reads are bank-clean. Per-row lanes map
    // to distinct slot mod 8 -> conflict-free ds_write; global reads form
    // 128B clusters per 8-lane group.
    if (t < span) srcs_sh[t] = srcs[eb + t];
    for (int base = 0; base < span; base += 32) {
      int r = base + rR;
      if (r < span) {
        const float* tr = tf + (long)sorted[eb + r] * DD;
        float4 v0 = *(const float4*)(tr + (cL + 0) * 4);
        float4 v1 = *(const float4*)(tr + (cL + 8) * 4);
        float4 v2 = *(const float4*)(tr + (cL + 16) * 4);
        float4 v3 = *(const float4*)(tr + (cL + 24) * 4);
        int sw8 = r & 7;
        float* rb = t_lds + r * DD;
        *(float4*)(rb + (((cL + 0) ^ sw8) << 2)) = v0;
        *(float4*)(rb + (((cL + 8) ^ sw8) << 2)) = v1;
        *(float4*)(rb + (((cL + 16) ^ sw8) << 2)) = v2;
        *(float4*)(rb + (((cL + 24) ^ sw8) << 2)) = v3;
      }
    }
    __syncthreads();

    // ---- Phase A: 16 edges/pass from LDS; sims vs ce-in-VGPR ----
    for (int r0 = 0; r0 < span; r0 += 16) {
      int el = r0 + elA;
      if (el < span) {
        int sw8 = el & 7;
        const float* rb = t_lds + el * DD;
        float4 t0 = *(const float4*)(rb + ((jA ^ sw8) << 2));
        float4 t1 = *(const float4*)(rb + ((16 + (jA ^ sw8)) << 2));
        int src = srcs_sh[el];
        const float* pr = p + (long)src * DD;
        float4 p0 = *(const float4*)(pr + jA * 4);
        float4 p1 = *(const float4*)(pr + (16 + jA) * 4);
        float a = dot4(t0, p0) + dot4(t1, p1);
        float sims[NC];
        #pragma unroll
        for (int c = 0; c < NC; c++)
          sims[c] = dot4(t0, ceg[c][0]) + dot4(t1, ceg[c][1]);
        #pragma unroll
        for (int c = 0; c < NC; c++) {
          sims[c] += __shfl_xor(sims[c], 1);
          sims[c] += __shfl_xor(sims[c], 2);
          sims[c] += __shfl_xor(sims[c], 4);
          sims[c] += __shfl_xor(sims[c], 8);
        }
        a += __shfl_xor(a, 1);
        a += __shfl_xor(a, 2);
        a += __shfl_xor(a, 4);
        a += __shfl_xor(a, 8);
        if (jA == 0) {
          float best = sims[0]; int bc = 0;
          #pragma unroll
          for (int c = 1; c < NC; c++) if (sims[c] > best) { best = sims[c]; bc = c; }
          float ex = expf((a + qb_sh[src - s0]) * SCALEF);
          exf_sh[el] = ex; cli_sh[el] = bc;
          atomicAdd(&D_sh[(src - s0) * NC + bc], ex);
          atomicAdd(&C_sh[(src - s0) * NC + bc], 1);
        }
      }
    }
    __syncthreads();

    // ---- Phase B: parallel scale ----
    if (t < span) {
      int l = (srcs_sh[t] - s0) * NC + cli_sh[t];
      scl_sh[t] = exf_sh[t] * __builtin_amdgcn_rcpf(D_sh[l] * (float)C_sh[l]);
    }
    __syncthreads();

    // ---- Phase C: register-accumulated segmented sums, float4 columns ----
    for (int k = team; k < nN; k += 8) {
      float4 r = {0.f, 0.f, 0.f, 0.f};
      int e1 = offL_sh[k] + cntL_sh[k];
      for (int e = offL_sh[k]; e < e1; e++) {
        float s = scl_sh[e];
        const float4 tv = *(const float4*)(t_lds + e * DD + ((c4 ^ (e & 7)) << 2));
        r.x += s * tv.x; r.y += s * tv.y; r.z += s * tv.z; r.w += s * tv.w;
      }
      long n = s0 + k;
      *(float4*)(agg + n * DD + c4 * 4) = r;
      if (c4 == 0) {
        float ssw = 0.f; int mk = 0;
        #pragma unroll
        for (int c = 0; c < NC; c++) {
          int cc = C_sh[k * NC + c];
          if (cc > 0) { mk |= 1 << c; ssw += __builtin_amdgcn_rcpf((float)cc); }
        }
        sw[n] = ssw; msk |= mk;
      }
    }
    __syncthreads();
    s0 += nN;
  }
  if ((t & 31) == 0 && msk) atomicOr(&maskArr[b & 255], msk);
}

// --- out = relu((agg @ Wvo + sw*bvo) * inv_nne + bo); inv_nne from maskArr ---
__global__ __launch_bounds__(256) void k_out(
    const float* __restrict__ agg, const float* __restrict__ Wvo,
    const float* __restrict__ bvo, const float* __restrict__ sw,
    const float* __restrict__ bo, const int* __restrict__ maskArr,
    float* __restrict__ out) {
  __shared__ float a_lds[64 * DD];
  __shared__ float sw_lds[64];
  __shared__ int morw[4];
  int t = threadIdx.x;
  int mv = maskArr[t];
  for (int o = 1; o < 64; o <<= 1) mv |= __shfl_xor(mv, o);
  if ((t & 63) == 0) morw[t >> 6] = mv;
  long row0 = (long)blockIdx.x * 64;
  for (int it = 0; it < 8; it++) {
    int idx = (it * 256 + t) * 4;
    long r = row0 + idx / DD;
    float4 v = {0.f, 0.f, 0.f, 0.f};
    if (r < NN) v = *(const float4*)(agg + r * DD + (idx % DD));
    *(float4*)(a_lds + idx) = v;
  }
  if (t < 64) {
    long r = row0 + t;
    sw_lds[t] = (r < NN) ? sw[r] : 0.f;
  }
  __syncthreads();
  int full = morw[0] | morw[1] | morw[2] | morw[3];
  int nne = __popc(full); if (nne == 0) nne = 1;
  float inv = 1.0f / (float)nne;
  int cg = t % 32, rg = t / 32;
  int col0 = cg * 4, r0 = rg * 8;
  float acc[8][4];
  for (int r = 0; r < 8; r++) for (int c = 0; c < 4; c++) acc[r][c] = 0.f;
  for (int k = 0; k < DD; k++) {
    float4 b4 = *(const float4*)(Wvo + k * DD + col0);
    for (int r = 0; r < 8; r++) {
      float a = a_lds[(r0 + r) * DD + k];
      acc[r][0] += a * b4.x; acc[r][1] += a * b4.y;
      acc[r][2] += a * b4.z; acc[r][3] += a * b4.w;
    }
  }
  float4 bv4 = *(const float4*)(bvo + col0);
  float4 bo4 = *(const float4*)(bo + col0);
  for (int r = 0; r < 8; r++) {
    long row = row0 + r0 + r;
    if (row < NN) {
      float s = sw_lds[r0 + r];
      float4 o;
      o.x = fmaxf((acc[r][0] + s * bv4.x) * inv + bo4.x, 0.f);
      o.y = fmaxf((acc[r][1] + s * bv4.y) * inv + bo4.y, 0.f);
      o.z = fmaxf((acc[r][2] + s * bv4.z) * inv + bo4.z, 0.f);
      o.w = fmaxf((acc[r][3] + s * bv4.w) * inv + bo4.w, 0.f);
      *(float4*)(out + row * DD + col0) = o;
    }
  }
}

extern "C" void kernel_launch(void* const* d_in, const int* in_sizes, int n_in,
                              void* d_out, int out_size, void* d_ws, size_t ws_size,
                              hipStream_t stream) {
  const float* nf = (const float*)d_in[0];
  const float* tf = (const float*)d_in[1];
  // d_in[2] = context_feat: unused by the reference
  const int*   ei = (const int*)d_in[3];   // row 0 = src
  const float* Wq = (const float*)d_in[4];
  const float* bq = (const float*)d_in[5];
  const float* Wk = (const float*)d_in[6];
  const float* bk = (const float*)d_in[7];
  const float* Wv = (const float*)d_in[8];
  const float* bv = (const float*)d_in[9];
  const float* ce = (const float*)d_in[10];
  const float* Wo = (const float*)d_in[11];
  const float* bo = (const float*)d_in[12];
  float* out = (float*)d_out;

  float* ws  = (float*)d_ws;
  int*   node_cnt = (int*)(ws + OFF_NODECNT);
  int*   fill     = (int*)(ws + OFF_FILL);
  int*   maskArr  = (int*)(ws + OFF_MASK);
  int*   node_off = (int*)(ws + OFF_NODEOFF);
  int*   partial  = (int*)(ws + OFF_PARTIAL);
  int*   blockFirst = (int*)(ws + OFF_BF);
  float* bqk      = ws + OFF_BQK;
  float* bvo      = ws + OFF_BVO;
  float* wqbk     = ws + OFF_WQBK;
  float* c0       = ws + OFF_C0;
  float* Wqk      = ws + OFF_WQK;
  float* Wvo      = ws + OFF_WVO;
  float* qb       = ws + OFF_QB;
  int*   sorted   = (int*)(ws + OFF_SORTED);
  int*   srcs     = (int*)(ws + OFF_SRCS);
  float* sw       = ws + OFF_SW;
  float* p        = ws + OFF_P;   // [N,128]
  float* agg      = ws + OFF_P;   // aliased (ownership-safe)

  hipMemsetAsync(d_ws, 0, (size_t)ZERO_ELEMS * 4, stream);

  k_pre_count<<<129 + EDGE_BLKS, 256, 0, stream>>>(
      Wq, bq, Wk, bk, Wv, bv, Wo, ei, node_cnt, Wqk, bqk, Wvo, bvo, wqbk, c0);
  k_p<<<(NN + 63) / 64, 256, 0, stream>>>(nf, Wqk, bqk, wqbk, c0, p, qb);
  k_scan1<<<196, 256, 0, stream>>>(node_cnt, partial);
  k_scan2<<<1, 256, 0, stream>>>(partial);
  k_scan3<<<196, 256, 0, stream>>>(node_cnt, partial, node_off);
  k_scatter<<<EDGE_BLKS + BS_BLKS, 256, 0, stream>>>(ei, node_off, fill, sorted,
                                                     srcs, blockFirst);
  k_fused7<<<NWIN, 256, 0, stream>>>(tf, sorted, srcs, node_off, node_cnt,
                                     blockFirst, ce, p, qb, maskArr, agg, sw);
  k_out<<<(NN + 63) / 64, 256, 0, stream>>>(agg, Wvo, bvo, sw, bo, maskArr, out);
}